// Round 1
// baseline (1100.265 us; speedup 1.0000x reference)
//
#include <hip/hip_runtime.h>
#include <hip/hip_bf16.h>

// Problem constants
#define NTOK 4096      // B*T
#define DDIM 1024
#define GG 4
#define EE 4
#define FF 4096
#define NEXP 16        // G*E
#define OUT_ELEMS 4194304        // N*D
#define GL_OFF 4194304           // group_logits offset in d_out (floats)
#define ENT_OFF 4210688          // entropy offset

typedef float f32x4 __attribute__((ext_vector_type(4)));
typedef short short8 __attribute__((ext_vector_type(8)));

__device__ inline unsigned short f2bf(float f) {
  unsigned int u = __float_as_uint(f);
  unsigned int rounding = 0x7FFFu + ((u >> 16) & 1u);
  return (unsigned short)((u + rounding) >> 16);
}
__device__ inline unsigned int pack2(float f0, float f1) {
  return (unsigned int)f2bf(f0) | ((unsigned int)f2bf(f1) << 16);
}

// ---------------- x -> bf16 conversion ----------------
__global__ void cvt_kernel(const float* __restrict__ x, unsigned short* __restrict__ xb) {
  int idx = blockIdx.x * 256 + threadIdx.x;   // one uint4 (8 bf16) per thread
  const float4* p = reinterpret_cast<const float4*>(x) + (size_t)idx * 2;
  float4 a = p[0], b = p[1];
  uint4 v;
  v.x = pack2(a.x, a.y); v.y = pack2(a.z, a.w);
  v.z = pack2(b.x, b.y); v.w = pack2(b.z, b.w);
  reinterpret_cast<uint4*>(xb)[idx] = v;
}

// ---------------- routing ----------------
__global__ __launch_bounds__(256) void routing_kernel(
    const float* __restrict__ x, const float* __restrict__ Wg,
    const float* __restrict__ We, float* __restrict__ out,
    int* __restrict__ cnt, int* __restrict__ tokL, int* __restrict__ hrwL,
    float* __restrict__ wslot) {
  int wave = threadIdx.x >> 6, lane = threadIdx.x & 63;
  int token = blockIdx.x * 4 + wave;
  const float4* xr = reinterpret_cast<const float4*>(x + (size_t)token * DDIM);
  float4 xv[4];
#pragma unroll
  for (int c = 0; c < 4; c++) xv[c] = xr[c * 64 + lane];

  auto dotrow = [&](const float* w) -> float {
    const float4* w4 = reinterpret_cast<const float4*>(w);
    float s = 0.f;
#pragma unroll
    for (int c = 0; c < 4; c++) {
      float4 wv = w4[c * 64 + lane];
      s += xv[c].x * wv.x + xv[c].y * wv.y + xv[c].z * wv.z + xv[c].w * wv.w;
    }
#pragma unroll
    for (int off = 32; off; off >>= 1) s += __shfl_xor(s, off, 64);
    return s;
  };

  float gl[GG];
#pragma unroll
  for (int g = 0; g < GG; g++) gl[g] = dotrow(Wg + g * DDIM);

  // top-2 groups (ties -> lower index, strict >)
  int g0 = 0;
  for (int g = 1; g < GG; g++) if (gl[g] > gl[g0]) g0 = g;
  int g1 = -1;
  for (int g = 0; g < GG; g++) { if (g == g0) continue; if (g1 < 0 || gl[g] > gl[g1]) g1 = g; }
  float e1 = __expf(gl[g1] - gl[g0]);
  float inv = 1.f / (1.f + e1);
  float w0 = inv, w1 = e1 * inv;

  // top-1 expert within each selected group
  int gsel[2] = {g0, g1};
  float wsel[2] = {w0, w1};
  int esel[2];
#pragma unroll
  for (int r = 0; r < 2; r++) {
    float el[EE];
#pragma unroll
    for (int e = 0; e < EE; e++) el[e] = dotrow(We + ((size_t)gsel[r] * EE + e) * DDIM);
    int best = 0;
    for (int e = 1; e < EE; e++) if (el[e] > el[best]) best = e;
    esel[r] = best;
  }

  // entropy of softmax over all 4 group logits
  float m = gl[0];
  for (int g = 1; g < GG; g++) m = fmaxf(m, gl[g]);
  float se = 0.f;
  for (int g = 0; g < GG; g++) se += __expf(gl[g] - m);
  float lse = __logf(se);
  float ent = 0.f;
  for (int g = 0; g < GG; g++) {
    float lp = gl[g] - m - lse;
    ent -= __expf(lp) * lp;
  }

  if (lane == 0) {
    for (int g = 0; g < GG; g++) out[GL_OFF + token * GG + g] = gl[g];
    atomicAdd(out + ENT_OFF, ent * (1.0f / NTOK));
    for (int r = 0; r < 2; r++) {
      int ge = gsel[r] * EE + esel[r];
      int pos = atomicAdd(cnt + ge, 1);
      tokL[ge * NTOK + pos] = token;
      hrwL[ge * NTOK + pos] = r * NTOK + token;
      wslot[r * NTOK + token] = wsel[r];
    }
  }
}

// ---------------- GEMM pass 1: H = gelu(Xg @ W1^T) ----------------
#define LDSP 40

__global__ __launch_bounds__(256) void up_kernel(
    const unsigned short* __restrict__ xb, const float* __restrict__ W1,
    const int* __restrict__ cnt, const int* __restrict__ tokL,
    const int* __restrict__ hrwL, unsigned short* __restrict__ H) {
  int ge = blockIdx.z, mt = blockIdx.y;
  int count = cnt[ge];
  if (mt * 64 >= count) return;
  int f0 = blockIdx.x * 64;

  __shared__ short As[64 * LDSP];
  __shared__ short Bs[64 * LDSP];
  __shared__ int rowsS[64];
  __shared__ int destS[64];

  int t = threadIdx.x;
  if (t < 64) {
    int i = mt * 64 + t;
    bool valid = i < count;
    rowsS[t] = valid ? tokL[ge * NTOK + i] : 0;
    destS[t] = valid ? hrwL[ge * NTOK + i] : -1;
  }
  __syncthreads();

  int srow = t >> 2;
  int schunk = (t & 3) * 8;
  const unsigned short* aptr = xb + (size_t)rowsS[srow] * DDIM + schunk;
  const float* bptr = W1 + ((size_t)ge * FF + (f0 + srow)) * DDIM + schunk;
  short* aw = &As[srow * LDSP + schunk];
  short* bw = &Bs[srow * LDSP + schunk];

  int wv = t >> 6, lane = t & 63;
  int m0 = wv * 16;
  int kg = (lane >> 4) * 8;
  const short8* afp = reinterpret_cast<const short8*>(&As[(m0 + (lane & 15)) * LDSP + kg]);

  f32x4 acc[4] = {};

  for (int kb = 0; kb < DDIM; kb += 32) {
    uint4 av = *reinterpret_cast<const uint4*>(aptr + kb);
    float4 b0 = *reinterpret_cast<const float4*>(bptr + kb);
    float4 b1 = *reinterpret_cast<const float4*>(bptr + kb + 4);
    *reinterpret_cast<uint4*>(aw) = av;
    uint4 bv;
    bv.x = pack2(b0.x, b0.y); bv.y = pack2(b0.z, b0.w);
    bv.z = pack2(b1.x, b1.y); bv.w = pack2(b1.z, b1.w);
    *reinterpret_cast<uint4*>(bw) = bv;
    __syncthreads();
    short8 af = *afp;
#pragma unroll
    for (int j = 0; j < 4; j++) {
      short8 bf = *reinterpret_cast<const short8*>(&Bs[(j * 16 + (lane & 15)) * LDSP + kg]);
      acc[j] = __builtin_amdgcn_mfma_f32_16x16x32_bf16(af, bf, acc[j], 0, 0, 0);
    }
    __syncthreads();
  }

  int rl = (lane >> 4) * 4;
  int col = lane & 15;
#pragma unroll
  for (int j = 0; j < 4; j++) {
    int f = f0 + j * 16 + col;
#pragma unroll
    for (int i2 = 0; i2 < 4; i2++) {
      int hr = destS[m0 + rl + i2];
      if (hr >= 0) {
        float v = acc[j][i2];
        float gel = 0.5f * v * (1.0f + erff(v * 0.70710678118654752f));
        H[(size_t)hr * FF + f] = f2bf(gel);
      }
    }
  }
}

// ---------------- GEMM pass 2: Y = Hg @ W2^T ----------------
__global__ __launch_bounds__(256) void down_kernel(
    const unsigned short* __restrict__ H, const float* __restrict__ W2,
    const int* __restrict__ cnt, const int* __restrict__ hrwL,
    float* __restrict__ Y) {
  int ge = blockIdx.z, mt = blockIdx.y;
  int count = cnt[ge];
  if (mt * 64 >= count) return;
  int d0 = blockIdx.x * 64;

  __shared__ short As[64 * LDSP];
  __shared__ short Bs[64 * LDSP];
  __shared__ int rowsS[64];

  int t = threadIdx.x;
  if (t < 64) {
    int i = mt * 64 + t;
    bool valid = i < count;
    rowsS[t] = valid ? hrwL[ge * NTOK + i] : -1;
  }
  __syncthreads();

  int srow = t >> 2;
  int schunk = (t & 3) * 8;
  int arow = rowsS[srow] < 0 ? 0 : rowsS[srow];
  const unsigned short* aptr = H + (size_t)arow * FF + schunk;
  const float* bptr = W2 + ((size_t)ge * DDIM + (d0 + srow)) * FF + schunk;
  short* aw = &As[srow * LDSP + schunk];
  short* bw = &Bs[srow * LDSP + schunk];

  int wv = t >> 6, lane = t & 63;
  int m0 = wv * 16;
  int kg = (lane >> 4) * 8;
  const short8* afp = reinterpret_cast<const short8*>(&As[(m0 + (lane & 15)) * LDSP + kg]);

  f32x4 acc[4] = {};

  for (int kb = 0; kb < FF; kb += 32) {
    uint4 av = *reinterpret_cast<const uint4*>(aptr + kb);
    float4 b0 = *reinterpret_cast<const float4*>(bptr + kb);
    float4 b1 = *reinterpret_cast<const float4*>(bptr + kb + 4);
    *reinterpret_cast<uint4*>(aw) = av;
    uint4 bv;
    bv.x = pack2(b0.x, b0.y); bv.y = pack2(b0.z, b0.w);
    bv.z = pack2(b1.x, b1.y); bv.w = pack2(b1.z, b1.w);
    *reinterpret_cast<uint4*>(bw) = bv;
    __syncthreads();
    short8 af = *afp;
#pragma unroll
    for (int j = 0; j < 4; j++) {
      short8 bf = *reinterpret_cast<const short8*>(&Bs[(j * 16 + (lane & 15)) * LDSP + kg]);
      acc[j] = __builtin_amdgcn_mfma_f32_16x16x32_bf16(af, bf, acc[j], 0, 0, 0);
    }
    __syncthreads();
  }

  int rl = (lane >> 4) * 4;
  int col = lane & 15;
#pragma unroll
  for (int j = 0; j < 4; j++) {
    int d = d0 + j * 16 + col;
#pragma unroll
    for (int i2 = 0; i2 < 4; i2++) {
      int hr = rowsS[m0 + rl + i2];
      if (hr >= 0) Y[(size_t)hr * DDIM + d] = acc[j][i2];
    }
  }
}

// ---------------- combine: out = w0*Y0 + w1*Y1 ----------------
__global__ void combine_kernel(const float* __restrict__ Y,
                               const float* __restrict__ wslot,
                               float* __restrict__ out) {
  int idx = blockIdx.x * 256 + threadIdx.x;    // one float4 per thread
  int token = idx >> 8;                        // 256 float4 per row
  float w0 = wslot[token], w1 = wslot[NTOK + token];
  float4 a = reinterpret_cast<const float4*>(Y)[idx];
  float4 b = reinterpret_cast<const float4*>(Y + (size_t)NTOK * DDIM)[idx];
  float4 o;
  o.x = w0 * a.x + w1 * b.x;
  o.y = w0 * a.y + w1 * b.y;
  o.z = w0 * a.z + w1 * b.z;
  o.w = w0 * a.w + w1 * b.w;
  reinterpret_cast<float4*>(out)[idx] = o;
}

extern "C" void kernel_launch(void* const* d_in, const int* in_sizes, int n_in,
                              void* d_out, int out_size, void* d_ws, size_t ws_size,
                              hipStream_t stream) {
  const float* x  = (const float*)d_in[0];
  const float* Wg = (const float*)d_in[1];
  const float* We = (const float*)d_in[2];
  const float* W1 = (const float*)d_in[3];
  const float* W2 = (const float*)d_in[4];
  float* out = (float*)d_out;
  char* ws = (char*)d_ws;

  // workspace layout
  int* cnt = (int*)(ws);                               // 64 B (zeroed)
  int* tokL = (int*)(ws + 1024);                       // 16*4096*4
  int* hrwL = (int*)(ws + 1024 + 262144);              // 16*4096*4
  float* wslot = (float*)(ws + 1024 + 524288);         // 2*4096*4
  unsigned short* xb = (unsigned short*)(ws + (1 << 20));            // 8 MB
  unsigned short* H  = (unsigned short*)(ws + (1 << 20) + 8388608);  // 67 MB
  float* Y = (float*)(ws + (1 << 20) + 8388608 + 67108864);          // 33.5 MB

  hipMemsetAsync(d_out, 0, (size_t)out_size * sizeof(float), stream);
  hipMemsetAsync(ws, 0, 1024, stream);

  cvt_kernel<<<2048, 256, 0, stream>>>(x, xb);
  routing_kernel<<<1024, 256, 0, stream>>>(x, Wg, We, out, cnt, tokL, hrwL, wslot);
  up_kernel<<<dim3(FF / 64, 64, NEXP), 256, 0, stream>>>(xb, W1, cnt, tokL, hrwL, H);
  down_kernel<<<dim3(DDIM / 64, 64, NEXP), 256, 0, stream>>>(H, W2, cnt, hrwL, Y);
  combine_kernel<<<4096, 256, 0, stream>>>(Y, wslot, out);
}